// Round 1
// baseline (733.636 us; speedup 1.0000x reference)
//
#include <hip/hip_runtime.h>
#include <hip/hip_bf16.h>

typedef __attribute__((ext_vector_type(8))) short bf16x8;
typedef __attribute__((ext_vector_type(4))) float f32x4;
typedef __attribute__((ext_vector_type(4))) short short4_t;
typedef __attribute__((ext_vector_type(4))) float float4_t;

#define MFMA16(a, b, c) __builtin_amdgcn_mfma_f32_16x16x32_bf16((a), (b), (c), 0, 0, 0)

__device__ __forceinline__ unsigned short f2bf(float f) {
    unsigned u = __builtin_bit_cast(unsigned, f);
    u += 0x7fffu + ((u >> 16) & 1u);   // round-to-nearest-even
    return (unsigned short)(u >> 16);
}

__device__ __forceinline__ short4_t pack4(float4_t v) {
    short4_t r;
    r[0] = (short)f2bf(v[0]);
    r[1] = (short)f2bf(v[1]);
    r[2] = (short)f2bf(v[2]);
    r[3] = (short)f2bf(v[3]);
    return r;
}

// ---------------------------------------------------------------------------
// Projection kernel: out = in @ W^T + b  (+ optional LayerNorm), 4 modes in
// one launch (grid 1024 = 4 modes x 256 row-blocks of 32).
//  mode 0: queries@Wv^T+bv -> f32 q_proto (output 0)
//  mode 1: support@Wv^T+bv -> bf16 VsT (transposed [512][8192])
//  mode 2: LN(support@Wk^T+bk) -> bf16 Ks [8192][512]
//  mode 3: LN(queries@Wq^T+bq) -> bf16 Qs [8192][512]
// BM=32, BK=32, 4 waves; wave w owns out-cols [w*128, w*128+128).
// ---------------------------------------------------------------------------
__global__ __launch_bounds__(256, 2) void proj_kernel(
    const float* __restrict__ support, const float* __restrict__ queries,
    const float* __restrict__ Wq, const float* __restrict__ bq,
    const float* __restrict__ Wk, const float* __restrict__ bk,
    const float* __restrict__ Wv, const float* __restrict__ bv,
    const float* __restrict__ gamma, const float* __restrict__ beta,
    float* __restrict__ q_proto,
    unsigned short* __restrict__ Qs, unsigned short* __restrict__ Ks,
    unsigned short* __restrict__ VsT)
{
    const int mode = blockIdx.x >> 8;
    const int rowbase = (blockIdx.x & 255) * 32;
    const float* in; const float* W; const float* bias;
    if (mode == 0)      { in = queries; W = Wv; bias = bv; }
    else if (mode == 1) { in = support; W = Wv; bias = bv; }
    else if (mode == 2) { in = support; W = Wk; bias = bk; }
    else                { in = queries; W = Wq; bias = bq; }

    const int t = threadIdx.x;
    const int wv = t >> 6, l = t & 63, lg = l >> 4, ll = l & 15;

    // pad rows to 40 shorts (80B) -> worst ~2-way bank aliasing on b128 reads
    __shared__ unsigned short Alds[32][40];
    __shared__ unsigned short Blds[512][40];
    __shared__ float red[4][32][2];
    __shared__ float stats[32][2];

    f32x4 acc[2][8];
    #pragma unroll
    for (int i = 0; i < 2; ++i)
        #pragma unroll
        for (int j = 0; j < 8; ++j) acc[i][j] = (f32x4){0.f, 0.f, 0.f, 0.f};

    const int arow = t >> 3, akc = (t & 7) * 4;
    const float* aptr = in + (size_t)(rowbase + arow) * 1024 + akc;
    const float* bptr = W + (size_t)arow * 1024 + akc;

    // software pipeline: regs hold tile kt while LDS holds tile kt
    float4_t aReg = *(const float4_t*)aptr;
    float4_t bReg[16];
    #pragma unroll
    for (int c = 0; c < 16; ++c)
        bReg[c] = *(const float4_t*)(bptr + (size_t)c * 32 * 1024);

    for (int kt = 0; kt < 32; ++kt) {
        __syncthreads();
        *(short4_t*)&Alds[arow][akc] = pack4(aReg);
        #pragma unroll
        for (int c = 0; c < 16; ++c)
            *(short4_t*)&Blds[arow + c * 32][akc] = pack4(bReg[c]);
        __syncthreads();
        if (kt < 31) {   // issue next-tile loads; latency hides under MFMA
            const int kb = (kt + 1) * 32;
            aReg = *(const float4_t*)(aptr + kb);
            #pragma unroll
            for (int c = 0; c < 16; ++c)
                bReg[c] = *(const float4_t*)(bptr + (size_t)c * 32 * 1024 + kb);
        }
        bf16x8 af[2];
        #pragma unroll
        for (int mf = 0; mf < 2; ++mf)
            af[mf] = *(const bf16x8*)&Alds[mf * 16 + ll][lg * 8];
        #pragma unroll
        for (int nf = 0; nf < 8; ++nf) {
            bf16x8 bfr = *(const bf16x8*)&Blds[wv * 128 + nf * 16 + ll][lg * 8];
            acc[0][nf] = MFMA16(af[0], bfr, acc[0][nf]);
            acc[1][nf] = MFMA16(af[1], bfr, acc[1][nf]);
        }
    }

    float bvv[8];
    #pragma unroll
    for (int nf = 0; nf < 8; ++nf) bvv[nf] = bias[wv * 128 + nf * 16 + ll];

    float v[2][8][4];
    #pragma unroll
    for (int mf = 0; mf < 2; ++mf)
        #pragma unroll
        for (int nf = 0; nf < 8; ++nf)
            #pragma unroll
            for (int r = 0; r < 4; ++r)
                v[mf][nf][r] = acc[mf][nf][r] + bvv[nf];

    if (mode == 0) {
        #pragma unroll
        for (int mf = 0; mf < 2; ++mf)
            #pragma unroll
            for (int r = 0; r < 4; ++r) {
                const size_t row = rowbase + mf * 16 + lg * 4 + r;
                #pragma unroll
                for (int nf = 0; nf < 8; ++nf)
                    q_proto[row * 512 + wv * 128 + nf * 16 + ll] = v[mf][nf][r];
            }
    } else if (mode == 1) {
        #pragma unroll
        for (int mf = 0; mf < 2; ++mf)
            #pragma unroll
            for (int nf = 0; nf < 8; ++nf) {
                float4_t pv = {v[mf][nf][0], v[mf][nf][1], v[mf][nf][2], v[mf][nf][3]};
                const size_t col = wv * 128 + nf * 16 + ll;
                *(short4_t*)&VsT[col * 8192 + rowbase + mf * 16 + lg * 4] = pack4(pv);
            }
    } else {
        // LayerNorm over the 512 out-cols of each row
        #pragma unroll
        for (int mf = 0; mf < 2; ++mf)
            #pragma unroll
            for (int r = 0; r < 4; ++r) {
                float s = 0.f, q = 0.f;
                #pragma unroll
                for (int nf = 0; nf < 8; ++nf) { s += v[mf][nf][r]; q += v[mf][nf][r] * v[mf][nf][r]; }
                #pragma unroll
                for (int d = 1; d < 16; d <<= 1) { s += __shfl_xor(s, d); q += __shfl_xor(q, d); }
                if (ll == 0) { red[wv][mf * 16 + lg * 4 + r][0] = s; red[wv][mf * 16 + lg * 4 + r][1] = q; }
            }
        __syncthreads();
        if (t < 32) {
            float S = 0.f, Q = 0.f;
            #pragma unroll
            for (int w2 = 0; w2 < 4; ++w2) { S += red[w2][t][0]; Q += red[w2][t][1]; }
            const float mu = S * (1.f / 512.f);
            const float var = Q * (1.f / 512.f) - mu * mu;
            stats[t][0] = mu;
            stats[t][1] = rsqrtf(var + 1e-5f);
        }
        __syncthreads();
        unsigned short* dst = (mode == 2) ? Ks : Qs;
        float gv[8], bev[8];
        #pragma unroll
        for (int nf = 0; nf < 8; ++nf) {
            gv[nf] = gamma[wv * 128 + nf * 16 + ll];
            bev[nf] = beta[wv * 128 + nf * 16 + ll];
        }
        #pragma unroll
        for (int mf = 0; mf < 2; ++mf)
            #pragma unroll
            for (int r = 0; r < 4; ++r) {
                const int row = mf * 16 + lg * 4 + r;
                const float mu = stats[row][0], rs = stats[row][1];
                #pragma unroll
                for (int nf = 0; nf < 8; ++nf) {
                    const float o = (v[mf][nf][r] - mu) * rs * gv[nf] + bev[nf];
                    dst[(size_t)(rowbase + row) * 512 + wv * 128 + nf * 16 + ll] = f2bf(o);
                }
            }
    }
}

// ---------------------------------------------------------------------------
// Flash attention (no max-subtraction: LN bounds |score| <= sqrt(512)).
// BM=128 q-rows/block, BKV=64, 8 waves (512 thr), KV split 4-way.
// QK^T: wave w owns q-rows [w*16, w*16+16), all 64 kv cols; Q frags in regs.
// PV:   wave w owns out-cols [w*64, w*64+64), full P via swizzled LDS.
// Writes unnormalized partials Opart[sp] and row-sums lpart[sp].
// ---------------------------------------------------------------------------
__global__ __launch_bounds__(512, 2) void attn_kernel(
    const unsigned short* __restrict__ Qs, const unsigned short* __restrict__ Ks,
    const unsigned short* __restrict__ VsT,
    float* __restrict__ Opart, float* __restrict__ lpart)
{
    const int bid = blockIdx.x;
    // XCD-aware: split sp pinned to an XCD pair -> per-XCD KV set ~4MB (=L2)
    const int sp = (bid & 7) >> 1;
    const int qb = (bid >> 3) * 2 + (bid & 1);
    const int qbase = qb * 128;
    const int kv0 = sp * 2048;
    const int t = threadIdx.x;
    const int w = t >> 6, l = t & 63, lg = l >> 4, ll = l & 15;

    __shared__ unsigned short Plds[128][64];   // XOR-swizzled on 16B units

    bf16x8 qf[16];
    {
        const unsigned short* qrow = Qs + (size_t)(qbase + w * 16 + ll) * 512 + lg * 8;
        #pragma unroll
        for (int ks = 0; ks < 16; ++ks)
            qf[ks] = *(const bf16x8*)(qrow + ks * 32);
    }

    f32x4 oacc[8][4];
    #pragma unroll
    for (int i = 0; i < 8; ++i)
        #pragma unroll
        for (int j = 0; j < 4; ++j) oacc[i][j] = (f32x4){0.f, 0.f, 0.f, 0.f};
    float lrun[4] = {0.f, 0.f, 0.f, 0.f};
    const float scale = 0.044194173824159216f;  // 1/sqrt(512)

    for (int it = 0; it < 32; ++it) {
        const int kvb = kv0 + it * 64;
        f32x4 sacc[4];
        #pragma unroll
        for (int nf = 0; nf < 4; ++nf) sacc[nf] = (f32x4){0.f, 0.f, 0.f, 0.f};
        const unsigned short* kp = Ks + ((size_t)kvb + ll) * 512 + lg * 8;
        #pragma unroll
        for (int ks = 0; ks < 16; ++ks) {
            #pragma unroll
            for (int nf = 0; nf < 4; ++nf) {
                bf16x8 kf = *(const bf16x8*)(kp + (size_t)nf * 16 * 512 + ks * 32);
                sacc[nf] = MFMA16(qf[ks], kf, sacc[nf]);
            }
        }
        __syncthreads();   // previous PV done reading Plds
        #pragma unroll
        for (int r = 0; r < 4; ++r) {
            const int row = w * 16 + lg * 4 + r;
            float rsum = 0.f;
            #pragma unroll
            for (int nf = 0; nf < 4; ++nf) {
                const float p = __expf(sacc[nf][r] * scale);
                rsum += p;
                const int col = nf * 16 + ll;
                const int unit = (col >> 3) ^ (row & 7);
                Plds[row][unit * 8 + (col & 7)] = f2bf(p);
            }
            #pragma unroll
            for (int d = 1; d < 16; d <<= 1) rsum += __shfl_xor(rsum, d);
            lrun[r] += rsum;
        }
        __syncthreads();   // Plds ready
        #pragma unroll
        for (int ks = 0; ks < 2; ++ks) {
            bf16x8 vf[4];
            #pragma unroll
            for (int nf = 0; nf < 4; ++nf)
                vf[nf] = *(const bf16x8*)(VsT + (size_t)(w * 64 + nf * 16 + ll) * 8192 + kvb + ks * 32 + lg * 8);
            #pragma unroll
            for (int mf = 0; mf < 8; ++mf) {
                const int row = mf * 16 + ll;
                const int unit = (ks * 4 + lg) ^ (row & 7);
                bf16x8 pf = *(const bf16x8*)&Plds[row][unit * 8];
                #pragma unroll
                for (int nf = 0; nf < 4; ++nf)
                    oacc[mf][nf] = MFMA16(pf, vf[nf], oacc[mf][nf]);
            }
        }
    }

    const size_t obase = (size_t)sp * 8192 + qbase;
    #pragma unroll
    for (int mf = 0; mf < 8; ++mf)
        #pragma unroll
        for (int r = 0; r < 4; ++r) {
            const size_t row = obase + mf * 16 + lg * 4 + r;
            #pragma unroll
            for (int nf = 0; nf < 4; ++nf)
                Opart[row * 512 + w * 64 + nf * 16 + ll] = oacc[mf][nf][r];
        }
    if (ll == 0) {
        #pragma unroll
        for (int r = 0; r < 4; ++r)
            lpart[(size_t)sp * 8192 + qbase + w * 16 + lg * 4 + r] = lrun[r];
    }
}

// ---------------------------------------------------------------------------
// Merge: out2 = (sum_s Opart[s]) / (sum_s lpart[s]) -- no max bookkeeping.
// ---------------------------------------------------------------------------
__global__ __launch_bounds__(256) void merge_kernel(
    const float* __restrict__ Opart, const float* __restrict__ lpart,
    float* __restrict__ out2)
{
    const int idx = blockIdx.x * 256 + threadIdx.x;   // one float4 per thread
    const int q = idx >> 7;
    const int c = (idx & 127) * 4;
    float4_t a = {0.f, 0.f, 0.f, 0.f};
    float ls = 0.f;
    #pragma unroll
    for (int s = 0; s < 4; ++s) {
        float4_t vv = *(const float4_t*)(Opart + ((size_t)s * 8192 + q) * 512 + c);
        a += vv;
        ls += lpart[s * 8192 + q];
    }
    const float inv = 1.f / ls;
    *(float4_t*)(out2 + (size_t)q * 512 + c) = a * inv;
}

extern "C" void kernel_launch(void* const* d_in, const int* in_sizes, int n_in,
                              void* d_out, int out_size, void* d_ws, size_t ws_size,
                              hipStream_t stream)
{
    const float* support = (const float*)d_in[0];
    const float* queries = (const float*)d_in[1];
    const float* Wq = (const float*)d_in[2];
    const float* bq = (const float*)d_in[3];
    const float* Wk = (const float*)d_in[4];
    const float* bk = (const float*)d_in[5];
    const float* Wv = (const float*)d_in[6];
    const float* bv = (const float*)d_in[7];
    const float* gamma = (const float*)d_in[8];
    const float* beta = (const float*)d_in[9];

    float* out = (float*)d_out;
    float* q_proto = out;                       // output 0: [8192,512]
    float* out2 = out + (size_t)8192 * 512;     // output 1: [8192,512]

    char* ws = (char*)d_ws;
    unsigned short* Qs  = (unsigned short*)(ws);                      //  8 MB
    unsigned short* Ks  = (unsigned short*)(ws + ((size_t)8 << 20));  //  8 MB
    unsigned short* VsT = (unsigned short*)(ws + ((size_t)16 << 20)); //  8 MB
    float* Opart = (float*)(ws + ((size_t)24 << 20));                 // 64 MB
    float* lpart = (float*)(ws + ((size_t)88 << 20));                 // 128 KB

    proj_kernel<<<1024, 256, 0, stream>>>(support, queries, Wq, bq, Wk, bk, Wv, bv,
                                          gamma, beta, q_proto, Qs, Ks, VsT);
    attn_kernel<<<256, 512, 0, stream>>>(Qs, Ks, VsT, Opart, lpart);
    merge_kernel<<<4096, 256, 0, stream>>>(Opart, lpart, out2);
}

// Round 2
// 364.058 us; speedup vs baseline: 2.0152x; 2.0152x over previous
//
#include <hip/hip_runtime.h>
#include <hip/hip_bf16.h>

typedef __attribute__((ext_vector_type(8))) short bf16x8;
typedef __attribute__((ext_vector_type(4))) float f32x4;
typedef __attribute__((ext_vector_type(4))) short short4_t;
typedef __attribute__((ext_vector_type(4))) float float4_t;

#define MFMA16(a, b, c) __builtin_amdgcn_mfma_f32_16x16x32_bf16((a), (b), (c), 0, 0, 0)

__device__ __forceinline__ unsigned short f2bf(float f) {
    unsigned u = __builtin_bit_cast(unsigned, f);
    u += 0x7fffu + ((u >> 16) & 1u);   // round-to-nearest-even
    return (unsigned short)(u >> 16);
}

__device__ __forceinline__ short4_t pack4(float4_t v) {
    short4_t r;
    r[0] = (short)f2bf(v[0]);
    r[1] = (short)f2bf(v[1]);
    r[2] = (short)f2bf(v[2]);
    r[3] = (short)f2bf(v[3]);
    return r;
}

// async global->LDS, 16B per lane. LDS dest is wave-uniform base + lane*16.
__device__ __forceinline__ void gload_lds16(const void* g, void* l) {
    __builtin_amdgcn_global_load_lds(
        (const __attribute__((address_space(1))) unsigned int*)g,
        (__attribute__((address_space(3))) unsigned int*)l, 16, 0, 0);
}

// ---------------------------------------------------------------------------
// Projection kernel: out = in @ W^T + b  (+ optional LayerNorm), 4 modes in
// one launch (grid 1024 = 4 modes x 256 row-blocks of 32).
//  mode 0: queries@Wv^T+bv -> f32 q_proto (output 0)
//  mode 1: support@Wv^T+bv -> bf16 VsT (transposed [512][8192])
//  mode 2: LN(support@Wk^T+bk) -> bf16 Ks [8192][512]
//  mode 3: LN(queries@Wq^T+bq) -> bf16 Qs [8192][512]
// ---------------------------------------------------------------------------
__global__ __launch_bounds__(256, 2) void proj_kernel(
    const float* __restrict__ support, const float* __restrict__ queries,
    const float* __restrict__ Wq, const float* __restrict__ bq,
    const float* __restrict__ Wk, const float* __restrict__ bk,
    const float* __restrict__ Wv, const float* __restrict__ bv,
    const float* __restrict__ gamma, const float* __restrict__ beta,
    float* __restrict__ q_proto,
    unsigned short* __restrict__ Qs, unsigned short* __restrict__ Ks,
    unsigned short* __restrict__ VsT)
{
    const int mode = blockIdx.x >> 8;
    const int rowbase = (blockIdx.x & 255) * 32;
    const float* in; const float* W; const float* bias;
    if (mode == 0)      { in = queries; W = Wv; bias = bv; }
    else if (mode == 1) { in = support; W = Wv; bias = bv; }
    else if (mode == 2) { in = support; W = Wk; bias = bk; }
    else                { in = queries; W = Wq; bias = bq; }

    const int t = threadIdx.x;
    const int wv = t >> 6, l = t & 63, lg = l >> 4, ll = l & 15;

    __shared__ unsigned short Alds[32][40];
    __shared__ unsigned short Blds[512][40];
    __shared__ float red[4][32][2];
    __shared__ float stats[32][2];

    f32x4 acc[2][8];
    #pragma unroll
    for (int i = 0; i < 2; ++i)
        #pragma unroll
        for (int j = 0; j < 8; ++j) acc[i][j] = (f32x4){0.f, 0.f, 0.f, 0.f};

    const int arow = t >> 3, akc = (t & 7) * 4;
    const float* aptr = in + (size_t)(rowbase + arow) * 1024 + akc;
    const float* bptr = W + (size_t)arow * 1024 + akc;

    float4_t aReg = *(const float4_t*)aptr;
    float4_t bReg[16];
    #pragma unroll
    for (int c = 0; c < 16; ++c)
        bReg[c] = *(const float4_t*)(bptr + (size_t)c * 32 * 1024);

    for (int kt = 0; kt < 32; ++kt) {
        __syncthreads();
        *(short4_t*)&Alds[arow][akc] = pack4(aReg);
        #pragma unroll
        for (int c = 0; c < 16; ++c)
            *(short4_t*)&Blds[arow + c * 32][akc] = pack4(bReg[c]);
        __syncthreads();
        if (kt < 31) {
            const int kb = (kt + 1) * 32;
            aReg = *(const float4_t*)(aptr + kb);
            #pragma unroll
            for (int c = 0; c < 16; ++c)
                bReg[c] = *(const float4_t*)(bptr + (size_t)c * 32 * 1024 + kb);
        }
        bf16x8 af[2];
        #pragma unroll
        for (int mf = 0; mf < 2; ++mf)
            af[mf] = *(const bf16x8*)&Alds[mf * 16 + ll][lg * 8];
        #pragma unroll
        for (int nf = 0; nf < 8; ++nf) {
            bf16x8 bfr = *(const bf16x8*)&Blds[wv * 128 + nf * 16 + ll][lg * 8];
            acc[0][nf] = MFMA16(af[0], bfr, acc[0][nf]);
            acc[1][nf] = MFMA16(af[1], bfr, acc[1][nf]);
        }
    }

    float bvv[8];
    #pragma unroll
    for (int nf = 0; nf < 8; ++nf) bvv[nf] = bias[wv * 128 + nf * 16 + ll];

    float v[2][8][4];
    #pragma unroll
    for (int mf = 0; mf < 2; ++mf)
        #pragma unroll
        for (int nf = 0; nf < 8; ++nf)
            #pragma unroll
            for (int r = 0; r < 4; ++r)
                v[mf][nf][r] = acc[mf][nf][r] + bvv[nf];

    if (mode == 0) {
        #pragma unroll
        for (int mf = 0; mf < 2; ++mf)
            #pragma unroll
            for (int r = 0; r < 4; ++r) {
                const size_t row = rowbase + mf * 16 + lg * 4 + r;
                #pragma unroll
                for (int nf = 0; nf < 8; ++nf)
                    q_proto[row * 512 + wv * 128 + nf * 16 + ll] = v[mf][nf][r];
            }
    } else if (mode == 1) {
        #pragma unroll
        for (int mf = 0; mf < 2; ++mf)
            #pragma unroll
            for (int nf = 0; nf < 8; ++nf) {
                float4_t pv = {v[mf][nf][0], v[mf][nf][1], v[mf][nf][2], v[mf][nf][3]};
                const size_t col = wv * 128 + nf * 16 + ll;
                *(short4_t*)&VsT[col * 8192 + rowbase + mf * 16 + lg * 4] = pack4(pv);
            }
    } else {
        #pragma unroll
        for (int mf = 0; mf < 2; ++mf)
            #pragma unroll
            for (int r = 0; r < 4; ++r) {
                float s = 0.f, q = 0.f;
                #pragma unroll
                for (int nf = 0; nf < 8; ++nf) { s += v[mf][nf][r]; q += v[mf][nf][r] * v[mf][nf][r]; }
                #pragma unroll
                for (int d = 1; d < 16; d <<= 1) { s += __shfl_xor(s, d); q += __shfl_xor(q, d); }
                if (ll == 0) { red[wv][mf * 16 + lg * 4 + r][0] = s; red[wv][mf * 16 + lg * 4 + r][1] = q; }
            }
        __syncthreads();
        if (t < 32) {
            float S = 0.f, Q = 0.f;
            #pragma unroll
            for (int w2 = 0; w2 < 4; ++w2) { S += red[w2][t][0]; Q += red[w2][t][1]; }
            const float mu = S * (1.f / 512.f);
            const float var = Q * (1.f / 512.f) - mu * mu;
            stats[t][0] = mu;
            stats[t][1] = rsqrtf(var + 1e-5f);
        }
        __syncthreads();
        unsigned short* dst = (mode == 2) ? Ks : Qs;
        float gv[8], bev[8];
        #pragma unroll
        for (int nf = 0; nf < 8; ++nf) {
            gv[nf] = gamma[wv * 128 + nf * 16 + ll];
            bev[nf] = beta[wv * 128 + nf * 16 + ll];
        }
        #pragma unroll
        for (int mf = 0; mf < 2; ++mf)
            #pragma unroll
            for (int r = 0; r < 4; ++r) {
                const int row = mf * 16 + lg * 4 + r;
                const float mu = stats[row][0], rs = stats[row][1];
                #pragma unroll
                for (int nf = 0; nf < 8; ++nf) {
                    const float o = (v[mf][nf][r] - mu) * rs * gv[nf] + bev[nf];
                    dst[(size_t)(rowbase + row) * 512 + wv * 128 + nf * 16 + ll] = f2bf(o);
                }
            }
    }
}

// ---------------------------------------------------------------------------
// Flash attention v2: K-tile staged in LDS (double-buffered) via
// global_load_lds w=16 with XOR-preswizzled global source (G21 both-sides).
// BM=128 q-rows/block, BKV=64, 8 waves, KV split 4-way (grid 256, 1 blk/CU).
// Per iter: [issue stage it+1] -> QK^T(ds) -> P write -> bar -> PV -> bar.
// LDS: 2x64KB K dbuf + 16KB P = 144 KB.
// ---------------------------------------------------------------------------
__global__ __launch_bounds__(512, 2) void attn_kernel(
    const unsigned short* __restrict__ Qs, const unsigned short* __restrict__ Ks,
    const unsigned short* __restrict__ VsT,
    float* __restrict__ Opart, float* __restrict__ lpart)
{
    const int bid = blockIdx.x;
    const int sp = (bid & 7) >> 1;          // KV split pinned per XCD pair
    const int qb = (bid >> 3) * 2 + (bid & 1);
    const int qbase = qb * 128;
    const int kv0 = sp * 2048;
    const int t = threadIdx.x;
    const int w = t >> 6, l = t & 63, lg = l >> 4, ll = l & 15;

    __shared__ unsigned short Klds[2][64][512];   // 128 KB, src-preswizzled
    __shared__ unsigned short Plds[128][64];      // 16 KB, XOR-swizzled

    // Q fragments: persistent in registers (64 VGPR), reused all 32 iters
    bf16x8 qf[16];
    {
        const unsigned short* qrow = Qs + (size_t)(qbase + w * 16 + ll) * 512 + lg * 8;
        #pragma unroll
        for (int ks = 0; ks < 16; ++ks)
            qf[ks] = *(const bf16x8*)(qrow + ks * 32);
    }

    f32x4 oacc[8][4];
    #pragma unroll
    for (int i = 0; i < 8; ++i)
        #pragma unroll
        for (int j = 0; j < 4; ++j) oacc[i][j] = (f32x4){0.f, 0.f, 0.f, 0.f};
    float lrun[4] = {0.f, 0.f, 0.f, 0.f};
    const float scale = 0.044194173824159216f;  // 1/sqrt(512)

    // prologue: stage tile 0 into buf 0 (wave w stages rows w*8..w*8+8;
    // global source column-unit pre-swizzled by (l ^ (row&7)))
    #pragma unroll
    for (int rr = 0; rr < 8; ++rr) {
        const int r = w * 8 + rr;
        gload_lds16(Ks + (size_t)(kv0 + r) * 512 + ((l ^ (r & 7)) << 3),
                    &Klds[0][r][0]);
    }
    __syncthreads();   // drains vmcnt then barriers: tile 0 fully in LDS

    for (int it = 0; it < 32; ++it) {
        const int cur = it & 1;
        const int kvb = kv0 + it * 64;

        // issue next-tile staging (lands before end-of-iter __syncthreads)
        if (it < 31) {
            const int kvn = kvb + 64;
            #pragma unroll
            for (int rr = 0; rr < 8; ++rr) {
                const int r = w * 8 + rr;
                gload_lds16(Ks + (size_t)(kvn + r) * 512 + ((l ^ (r & 7)) << 3),
                            &Klds[cur ^ 1][r][0]);
            }
        }

        // QK^T: wave w owns q-rows [w*16,w*16+16), all 64 kv cols, K from LDS
        f32x4 sacc[4];
        #pragma unroll
        for (int nf = 0; nf < 4; ++nf) sacc[nf] = (f32x4){0.f, 0.f, 0.f, 0.f};
        #pragma unroll
        for (int ks = 0; ks < 16; ++ks) {
            const int u = ((ks * 4 + lg) ^ (ll & 7)) * 8;   // un-swizzle read
            #pragma unroll
            for (int nf = 0; nf < 4; ++nf) {
                bf16x8 kf = *(const bf16x8*)&Klds[cur][nf * 16 + ll][u];
                sacc[nf] = MFMA16(qf[ks], kf, sacc[nf]);
            }
        }

        // exp + P write (prev PV readers finished at prev iter's 2nd barrier)
        #pragma unroll
        for (int r = 0; r < 4; ++r) {
            const int row = w * 16 + lg * 4 + r;
            float rsum = 0.f;
            #pragma unroll
            for (int nf = 0; nf < 4; ++nf) {
                const float p = __expf(sacc[nf][r] * scale);
                rsum += p;
                const int col = nf * 16 + ll;
                const int unit = (col >> 3) ^ (row & 7);
                Plds[row][unit * 8 + (col & 7)] = f2bf(p);
            }
            #pragma unroll
            for (int d = 1; d < 16; d <<= 1) rsum += __shfl_xor(rsum, d);
            lrun[r] += rsum;
        }
        __syncthreads();   // P ready

        // PV: wave w owns out-cols [w*64,w*64+64), V direct from L2
        #pragma unroll
        for (int ks = 0; ks < 2; ++ks) {
            bf16x8 vf[4];
            #pragma unroll
            for (int nf = 0; nf < 4; ++nf)
                vf[nf] = *(const bf16x8*)(VsT + (size_t)(w * 64 + nf * 16 + ll) * 8192 + kvb + ks * 32 + lg * 8);
            #pragma unroll
            for (int mf = 0; mf < 8; ++mf) {
                const int row = mf * 16 + ll;
                const int unit = (ks * 4 + lg) ^ (row & 7);
                bf16x8 pf = *(const bf16x8*)&Plds[row][unit * 8];
                #pragma unroll
                for (int nf = 0; nf < 4; ++nf)
                    oacc[mf][nf] = MFMA16(pf, vf[nf], oacc[mf][nf]);
            }
        }
        __syncthreads();   // drains vmcnt: next K tile staged; P-reads done
    }

    const size_t obase = (size_t)sp * 8192 + qbase;
    #pragma unroll
    for (int mf = 0; mf < 8; ++mf)
        #pragma unroll
        for (int r = 0; r < 4; ++r) {
            const size_t row = obase + mf * 16 + lg * 4 + r;
            #pragma unroll
            for (int nf = 0; nf < 4; ++nf)
                Opart[row * 512 + w * 64 + nf * 16 + ll] = oacc[mf][nf][r];
        }
    if (ll == 0) {
        #pragma unroll
        for (int r = 0; r < 4; ++r)
            lpart[(size_t)sp * 8192 + qbase + w * 16 + lg * 4 + r] = lrun[r];
    }
}

// ---------------------------------------------------------------------------
// Merge: out2 = (sum_s Opart[s]) / (sum_s lpart[s])
// ---------------------------------------------------------------------------
__global__ __launch_bounds__(256) void merge_kernel(
    const float* __restrict__ Opart, const float* __restrict__ lpart,
    float* __restrict__ out2)
{
    const int idx = blockIdx.x * 256 + threadIdx.x;
    const int q = idx >> 7;
    const int c = (idx & 127) * 4;
    float4_t a = {0.f, 0.f, 0.f, 0.f};
    float ls = 0.f;
    #pragma unroll
    for (int s = 0; s < 4; ++s) {
        float4_t vv = *(const float4_t*)(Opart + ((size_t)s * 8192 + q) * 512 + c);
        a += vv;
        ls += lpart[s * 8192 + q];
    }
    const float inv = 1.f / ls;
    *(float4_t*)(out2 + (size_t)q * 512 + c) = a * inv;
}

extern "C" void kernel_launch(void* const* d_in, const int* in_sizes, int n_in,
                              void* d_out, int out_size, void* d_ws, size_t ws_size,
                              hipStream_t stream)
{
    const float* support = (const float*)d_in[0];
    const float* queries = (const float*)d_in[1];
    const float* Wq = (const float*)d_in[2];
    const float* bq = (const float*)d_in[3];
    const float* Wk = (const float*)d_in[4];
    const float* bk = (const float*)d_in[5];
    const float* Wv = (const float*)d_in[6];
    const float* bv = (const float*)d_in[7];
    const float* gamma = (const float*)d_in[8];
    const float* beta = (const float*)d_in[9];

    float* out = (float*)d_out;
    float* q_proto = out;                       // output 0: [8192,512]
    float* out2 = out + (size_t)8192 * 512;     // output 1: [8192,512]

    char* ws = (char*)d_ws;
    unsigned short* Qs  = (unsigned short*)(ws);                      //  8 MB
    unsigned short* Ks  = (unsigned short*)(ws + ((size_t)8 << 20));  //  8 MB
    unsigned short* VsT = (unsigned short*)(ws + ((size_t)16 << 20)); //  8 MB
    float* Opart = (float*)(ws + ((size_t)24 << 20));                 // 64 MB
    float* lpart = (float*)(ws + ((size_t)88 << 20));                 // 128 KB

    proj_kernel<<<1024, 256, 0, stream>>>(support, queries, Wq, bq, Wk, bk, Wv, bv,
                                          gamma, beta, q_proto, Qs, Ks, VsT);
    attn_kernel<<<256, 512, 0, stream>>>(Qs, Ks, VsT, Opart, lpart);
    merge_kernel<<<4096, 256, 0, stream>>>(Opart, lpart, out2);
}

// Round 3
// 337.019 us; speedup vs baseline: 2.1768x; 1.0802x over previous
//
#include <hip/hip_runtime.h>
#include <hip/hip_bf16.h>

typedef __attribute__((ext_vector_type(8))) short bf16x8;
typedef __attribute__((ext_vector_type(4))) float f32x4;
typedef __attribute__((ext_vector_type(4))) short short4_t;
typedef __attribute__((ext_vector_type(4))) float float4_t;

#define MFMA16(a, b, c) __builtin_amdgcn_mfma_f32_16x16x32_bf16((a), (b), (c), 0, 0, 0)

__device__ __forceinline__ unsigned short f2bf(float f) {
    unsigned u = __builtin_bit_cast(unsigned, f);
    u += 0x7fffu + ((u >> 16) & 1u);   // round-to-nearest-even
    return (unsigned short)(u >> 16);
}

__device__ __forceinline__ short4_t pack4(float4_t v) {
    short4_t r;
    r[0] = (short)f2bf(v[0]);
    r[1] = (short)f2bf(v[1]);
    r[2] = (short)f2bf(v[2]);
    r[3] = (short)f2bf(v[3]);
    return r;
}

// async global->LDS, 16B per lane. LDS dest is wave-uniform base + lane*16.
__device__ __forceinline__ void gload_lds16(const void* g, void* l) {
    __builtin_amdgcn_global_load_lds(
        (const __attribute__((address_space(1))) unsigned int*)g,
        (__attribute__((address_space(3))) unsigned int*)l, 16, 0, 0);
}

// ---------------------------------------------------------------------------
// Projection kernel: out = in @ W^T + b  (+ optional LayerNorm), 4 modes in
// one launch (grid 1024 = 4 modes x 256 row-blocks of 32).
//  mode 0: queries@Wv^T+bv -> f32 q_proto (output 0)
//  mode 1: support@Wv^T+bv -> bf16 VsT (transposed [512][8192])
//  mode 2: LN(support@Wk^T+bk) -> bf16 Ks [8192][512]
//  mode 3: LN(queries@Wq^T+bq) -> bf16 Qs [8192][512]
// ---------------------------------------------------------------------------
__global__ __launch_bounds__(256, 2) void proj_kernel(
    const float* __restrict__ support, const float* __restrict__ queries,
    const float* __restrict__ Wq, const float* __restrict__ bq,
    const float* __restrict__ Wk, const float* __restrict__ bk,
    const float* __restrict__ Wv, const float* __restrict__ bv,
    const float* __restrict__ gamma, const float* __restrict__ beta,
    float* __restrict__ q_proto,
    unsigned short* __restrict__ Qs, unsigned short* __restrict__ Ks,
    unsigned short* __restrict__ VsT)
{
    const int mode = blockIdx.x >> 8;
    const int rowbase = (blockIdx.x & 255) * 32;
    const float* in; const float* W; const float* bias;
    if (mode == 0)      { in = queries; W = Wv; bias = bv; }
    else if (mode == 1) { in = support; W = Wv; bias = bv; }
    else if (mode == 2) { in = support; W = Wk; bias = bk; }
    else                { in = queries; W = Wq; bias = bq; }

    const int t = threadIdx.x;
    const int wv = t >> 6, l = t & 63, lg = l >> 4, ll = l & 15;

    __shared__ unsigned short Alds[32][40];
    __shared__ unsigned short Blds[512][40];
    __shared__ float red[4][32][2];
    __shared__ float stats[32][2];

    f32x4 acc[2][8];
    #pragma unroll
    for (int i = 0; i < 2; ++i)
        #pragma unroll
        for (int j = 0; j < 8; ++j) acc[i][j] = (f32x4){0.f, 0.f, 0.f, 0.f};

    const int arow = t >> 3, akc = (t & 7) * 4;
    const float* aptr = in + (size_t)(rowbase + arow) * 1024 + akc;
    const float* bptr = W + (size_t)arow * 1024 + akc;

    float4_t aReg = *(const float4_t*)aptr;
    float4_t bReg[16];
    #pragma unroll
    for (int c = 0; c < 16; ++c)
        bReg[c] = *(const float4_t*)(bptr + (size_t)c * 32 * 1024);

    for (int kt = 0; kt < 32; ++kt) {
        __syncthreads();
        *(short4_t*)&Alds[arow][akc] = pack4(aReg);
        #pragma unroll
        for (int c = 0; c < 16; ++c)
            *(short4_t*)&Blds[arow + c * 32][akc] = pack4(bReg[c]);
        __syncthreads();
        if (kt < 31) {
            const int kb = (kt + 1) * 32;
            aReg = *(const float4_t*)(aptr + kb);
            #pragma unroll
            for (int c = 0; c < 16; ++c)
                bReg[c] = *(const float4_t*)(bptr + (size_t)c * 32 * 1024 + kb);
        }
        bf16x8 af[2];
        #pragma unroll
        for (int mf = 0; mf < 2; ++mf)
            af[mf] = *(const bf16x8*)&Alds[mf * 16 + ll][lg * 8];
        #pragma unroll
        for (int nf = 0; nf < 8; ++nf) {
            bf16x8 bfr = *(const bf16x8*)&Blds[wv * 128 + nf * 16 + ll][lg * 8];
            acc[0][nf] = MFMA16(af[0], bfr, acc[0][nf]);
            acc[1][nf] = MFMA16(af[1], bfr, acc[1][nf]);
        }
    }

    float bvv[8];
    #pragma unroll
    for (int nf = 0; nf < 8; ++nf) bvv[nf] = bias[wv * 128 + nf * 16 + ll];

    float v[2][8][4];
    #pragma unroll
    for (int mf = 0; mf < 2; ++mf)
        #pragma unroll
        for (int nf = 0; nf < 8; ++nf)
            #pragma unroll
            for (int r = 0; r < 4; ++r)
                v[mf][nf][r] = acc[mf][nf][r] + bvv[nf];

    if (mode == 0) {
        #pragma unroll
        for (int mf = 0; mf < 2; ++mf)
            #pragma unroll
            for (int r = 0; r < 4; ++r) {
                const size_t row = rowbase + mf * 16 + lg * 4 + r;
                #pragma unroll
                for (int nf = 0; nf < 8; ++nf)
                    q_proto[row * 512 + wv * 128 + nf * 16 + ll] = v[mf][nf][r];
            }
    } else if (mode == 1) {
        #pragma unroll
        for (int mf = 0; mf < 2; ++mf)
            #pragma unroll
            for (int nf = 0; nf < 8; ++nf) {
                float4_t pv = {v[mf][nf][0], v[mf][nf][1], v[mf][nf][2], v[mf][nf][3]};
                const size_t col = wv * 128 + nf * 16 + ll;
                *(short4_t*)&VsT[col * 8192 + rowbase + mf * 16 + lg * 4] = pack4(pv);
            }
    } else {
        #pragma unroll
        for (int mf = 0; mf < 2; ++mf)
            #pragma unroll
            for (int r = 0; r < 4; ++r) {
                float s = 0.f, q = 0.f;
                #pragma unroll
                for (int nf = 0; nf < 8; ++nf) { s += v[mf][nf][r]; q += v[mf][nf][r] * v[mf][nf][r]; }
                #pragma unroll
                for (int d = 1; d < 16; d <<= 1) { s += __shfl_xor(s, d); q += __shfl_xor(q, d); }
                if (ll == 0) { red[wv][mf * 16 + lg * 4 + r][0] = s; red[wv][mf * 16 + lg * 4 + r][1] = q; }
            }
        __syncthreads();
        if (t < 32) {
            float S = 0.f, Q = 0.f;
            #pragma unroll
            for (int w2 = 0; w2 < 4; ++w2) { S += red[w2][t][0]; Q += red[w2][t][1]; }
            const float mu = S * (1.f / 512.f);
            const float var = Q * (1.f / 512.f) - mu * mu;
            stats[t][0] = mu;
            stats[t][1] = rsqrtf(var + 1e-5f);
        }
        __syncthreads();
        unsigned short* dst = (mode == 2) ? Ks : Qs;
        float gv[8], bev[8];
        #pragma unroll
        for (int nf = 0; nf < 8; ++nf) {
            gv[nf] = gamma[wv * 128 + nf * 16 + ll];
            bev[nf] = beta[wv * 128 + nf * 16 + ll];
        }
        #pragma unroll
        for (int mf = 0; mf < 2; ++mf)
            #pragma unroll
            for (int r = 0; r < 4; ++r) {
                const int row = mf * 16 + lg * 4 + r;
                const float mu = stats[row][0], rs = stats[row][1];
                #pragma unroll
                for (int nf = 0; nf < 8; ++nf) {
                    const float o = (v[mf][nf][r] - mu) * rs * gv[nf] + bev[nf];
                    dst[(size_t)(rowbase + row) * 512 + wv * 128 + nf * 16 + ll] = f2bf(o);
                }
            }
    }
}

// ---------------------------------------------------------------------------
// Flash attention v3: K dbuf (2x64KB) AND P dbuf (2x16KB) -> ONE barrier per
// iteration. Between barriers a wave runs [PV(it) | stage(it+2) | QK^T(it+1)
// | P-write(it+1)] with no sync, so waves desynchronize and LDS/MFMA overlap.
// Hazards: stage(it+1)->K[(it+1)&1]: its last readers (QK^T(it-1)) are past
// barrier(it-1). P-write(it+2)->P[it&1]: all waves did PV(it) before
// barrier(it+1). __syncthreads drains vmcnt -> staged tile complete.
// LDS: 128KB K + 32KB P = 160KB (full CU; regs cap us at 1 block anyway).
// ---------------------------------------------------------------------------
__global__ __launch_bounds__(512, 2) void attn_kernel(
    const unsigned short* __restrict__ Qs, const unsigned short* __restrict__ Ks,
    const unsigned short* __restrict__ VsT,
    float* __restrict__ Opart, float* __restrict__ lpart)
{
    const int bid = blockIdx.x;
    const int sp = (bid & 7) >> 1;          // KV split pinned per XCD pair
    const int qb = (bid >> 3) * 2 + (bid & 1);
    const int qbase = qb * 128;
    const int kv0 = sp * 2048;
    const int t = threadIdx.x;
    const int w = t >> 6, l = t & 63, lg = l >> 4, ll = l & 15;

    __shared__ unsigned short Klds[2][64][512];   // 128 KB, src-preswizzled
    __shared__ unsigned short Plds[2][128][64];   // 32 KB, XOR-swizzled

    // Q fragments: persistent in registers (64 VGPR), reused all 32 iters
    bf16x8 qf[16];
    {
        const unsigned short* qrow = Qs + (size_t)(qbase + w * 16 + ll) * 512 + lg * 8;
        #pragma unroll
        for (int ks = 0; ks < 16; ++ks)
            qf[ks] = *(const bf16x8*)(qrow + ks * 32);
    }

    f32x4 oacc[8][4];
    #pragma unroll
    for (int i = 0; i < 8; ++i)
        #pragma unroll
        for (int j = 0; j < 4; ++j) oacc[i][j] = (f32x4){0.f, 0.f, 0.f, 0.f};
    float lrun[4] = {0.f, 0.f, 0.f, 0.f};
    const float scale = 0.044194173824159216f;  // 1/sqrt(512)

    // prologue: stage tile 0 into buf 0 (wave w stages rows w*8..w*8+8;
    // global source column-unit pre-swizzled by (l ^ (row&7)))
    #pragma unroll
    for (int rr = 0; rr < 8; ++rr) {
        const int r = w * 8 + rr;
        gload_lds16(Ks + (size_t)(kv0 + r) * 512 + ((l ^ (r & 7)) << 3),
                    &Klds[0][r][0]);
    }
    __syncthreads();   // drains vmcnt then barriers: tile 0 fully in LDS

    for (int it = 0; it < 32; ++it) {
        const int cur = it & 1;
        const int kvb = kv0 + it * 64;

        // issue next-tile staging; completion guaranteed by this iter's barrier
        if (it < 31) {
            const int kvn = kvb + 64;
            #pragma unroll
            for (int rr = 0; rr < 8; ++rr) {
                const int r = w * 8 + rr;
                gload_lds16(Ks + (size_t)(kvn + r) * 512 + ((l ^ (r & 7)) << 3),
                            &Klds[cur ^ 1][r][0]);
            }
        }

        // QK^T: wave w owns q-rows [w*16,w*16+16), all 64 kv cols, K from LDS
        f32x4 sacc[4];
        #pragma unroll
        for (int nf = 0; nf < 4; ++nf) sacc[nf] = (f32x4){0.f, 0.f, 0.f, 0.f};
        __builtin_amdgcn_s_setprio(1);
        #pragma unroll
        for (int ks = 0; ks < 16; ++ks) {
            const int u = ((ks * 4 + lg) ^ (ll & 7)) * 8;   // un-swizzle read
            #pragma unroll
            for (int nf = 0; nf < 4; ++nf) {
                bf16x8 kf = *(const bf16x8*)&Klds[cur][nf * 16 + ll][u];
                sacc[nf] = MFMA16(qf[ks], kf, sacc[nf]);
            }
        }
        __builtin_amdgcn_s_setprio(0);

        // exp + P write into P[cur] (its previous readers finished PV(it-2)
        // before barrier(it-1), which we are past)
        #pragma unroll
        for (int r = 0; r < 4; ++r) {
            const int row = w * 16 + lg * 4 + r;
            float rsum = 0.f;
            #pragma unroll
            for (int nf = 0; nf < 4; ++nf) {
                const float p = __expf(sacc[nf][r] * scale);
                rsum += p;
                const int col = nf * 16 + ll;
                const int unit = (col >> 3) ^ (row & 7);
                Plds[cur][row][unit * 8 + (col & 7)] = f2bf(p);
            }
            #pragma unroll
            for (int d = 1; d < 16; d <<= 1) rsum += __shfl_xor(rsum, d);
            lrun[r] += rsum;
        }

        __syncthreads();   // single barrier: P[cur] ready, K[cur^1] staged

        // PV: wave w owns out-cols [w*64,w*64+64), V direct from L2
        __builtin_amdgcn_s_setprio(1);
        #pragma unroll
        for (int ks = 0; ks < 2; ++ks) {
            bf16x8 vf[4];
            #pragma unroll
            for (int nf = 0; nf < 4; ++nf)
                vf[nf] = *(const bf16x8*)(VsT + (size_t)(w * 64 + nf * 16 + ll) * 8192 + kvb + ks * 32 + lg * 8);
            #pragma unroll
            for (int mf = 0; mf < 8; ++mf) {
                const int row = mf * 16 + ll;
                const int unit = (ks * 4 + lg) ^ (row & 7);
                bf16x8 pf = *(const bf16x8*)&Plds[cur][row][unit * 8];
                #pragma unroll
                for (int nf = 0; nf < 4; ++nf)
                    oacc[mf][nf] = MFMA16(pf, vf[nf], oacc[mf][nf]);
            }
        }
        __builtin_amdgcn_s_setprio(0);
    }

    const size_t obase = (size_t)sp * 8192 + qbase;
    #pragma unroll
    for (int mf = 0; mf < 8; ++mf)
        #pragma unroll
        for (int r = 0; r < 4; ++r) {
            const size_t row = obase + mf * 16 + lg * 4 + r;
            #pragma unroll
            for (int nf = 0; nf < 4; ++nf)
                Opart[row * 512 + w * 64 + nf * 16 + ll] = oacc[mf][nf][r];
        }
    if (ll == 0) {
        #pragma unroll
        for (int r = 0; r < 4; ++r)
            lpart[(size_t)sp * 8192 + qbase + w * 16 + lg * 4 + r] = lrun[r];
    }
}

// ---------------------------------------------------------------------------
// Merge: out2 = (sum_s Opart[s]) / (sum_s lpart[s])
// ---------------------------------------------------------------------------
__global__ __launch_bounds__(256) void merge_kernel(
    const float* __restrict__ Opart, const float* __restrict__ lpart,
    float* __restrict__ out2)
{
    const int idx = blockIdx.x * 256 + threadIdx.x;
    const int q = idx >> 7;
    const int c = (idx & 127) * 4;
    float4_t a = {0.f, 0.f, 0.f, 0.f};
    float ls = 0.f;
    #pragma unroll
    for (int s = 0; s < 4; ++s) {
        float4_t vv = *(const float4_t*)(Opart + ((size_t)s * 8192 + q) * 512 + c);
        a += vv;
        ls += lpart[s * 8192 + q];
    }
    const float inv = 1.f / ls;
    *(float4_t*)(out2 + (size_t)q * 512 + c) = a * inv;
}

extern "C" void kernel_launch(void* const* d_in, const int* in_sizes, int n_in,
                              void* d_out, int out_size, void* d_ws, size_t ws_size,
                              hipStream_t stream)
{
    const float* support = (const float*)d_in[0];
    const float* queries = (const float*)d_in[1];
    const float* Wq = (const float*)d_in[2];
    const float* bq = (const float*)d_in[3];
    const float* Wk = (const float*)d_in[4];
    const float* bk = (const float*)d_in[5];
    const float* Wv = (const float*)d_in[6];
    const float* bv = (const float*)d_in[7];
    const float* gamma = (const float*)d_in[8];
    const float* beta = (const float*)d_in[9];

    float* out = (float*)d_out;
    float* q_proto = out;                       // output 0: [8192,512]
    float* out2 = out + (size_t)8192 * 512;     // output 1: [8192,512]

    char* ws = (char*)d_ws;
    unsigned short* Qs  = (unsigned short*)(ws);                      //  8 MB
    unsigned short* Ks  = (unsigned short*)(ws + ((size_t)8 << 20));  //  8 MB
    unsigned short* VsT = (unsigned short*)(ws + ((size_t)16 << 20)); //  8 MB
    float* Opart = (float*)(ws + ((size_t)24 << 20));                 // 64 MB
    float* lpart = (float*)(ws + ((size_t)88 << 20));                 // 128 KB

    proj_kernel<<<1024, 256, 0, stream>>>(support, queries, Wq, bq, Wk, bk, Wv, bv,
                                          gamma, beta, q_proto, Qs, Ks, VsT);
    attn_kernel<<<256, 512, 0, stream>>>(Qs, Ks, VsT, Opart, lpart);
    merge_kernel<<<4096, 256, 0, stream>>>(Opart, lpart, out2);
}

// Round 4
// 295.649 us; speedup vs baseline: 2.4814x; 1.1399x over previous
//
#include <hip/hip_runtime.h>
#include <hip/hip_bf16.h>

typedef __attribute__((ext_vector_type(8))) short bf16x8;
typedef __attribute__((ext_vector_type(4))) float f32x4;
typedef __attribute__((ext_vector_type(4))) short short4_t;
typedef __attribute__((ext_vector_type(4))) float float4_t;

#define MFMA16(a, b, c) __builtin_amdgcn_mfma_f32_16x16x32_bf16((a), (b), (c), 0, 0, 0)

__device__ __forceinline__ unsigned short f2bf(float f) {
    unsigned u = __builtin_bit_cast(unsigned, f);
    u += 0x7fffu + ((u >> 16) & 1u);   // round-to-nearest-even
    return (unsigned short)(u >> 16);
}

__device__ __forceinline__ short4_t pack4(float4_t v) {
    short4_t r;
    r[0] = (short)f2bf(v[0]);
    r[1] = (short)f2bf(v[1]);
    r[2] = (short)f2bf(v[2]);
    r[3] = (short)f2bf(v[3]);
    return r;
}

// async global->LDS, 16B per lane. LDS dest is wave-uniform base + lane*16.
__device__ __forceinline__ void gload_lds16(const void* g, void* l) {
    __builtin_amdgcn_global_load_lds(
        (const __attribute__((address_space(1))) unsigned int*)g,
        (__attribute__((address_space(3))) unsigned int*)l, 16, 0, 0);
}

// ---------------------------------------------------------------------------
// proj_v: out = in @ Wv^T + bv for modes {0: queries->q_proto f32,
//         1: support->VsT bf16 transposed}.
// BM=128, BN=256, BK=32. grid 256 = 2 modes x 64 rowb x 2 colb. 8 waves.
// Wave grid 2r x 4c: wave owns 64 rows x 64 cols -> acc[4][4] (64 AGPR).
// W re-read per mode: 128 blocks*1MB = 128MB L2 (was 512MB).
// ---------------------------------------------------------------------------
__global__ __launch_bounds__(512, 2) void proj_v_kernel(
    const float* __restrict__ support, const float* __restrict__ queries,
    const float* __restrict__ Wv, const float* __restrict__ bv,
    float* __restrict__ q_proto, unsigned short* __restrict__ VsT)
{
    const int mode = blockIdx.x >> 7;
    const int rem = blockIdx.x & 127;
    const int rowbase = (rem >> 1) * 128;
    const int colbase = (rem & 1) * 256;
    const float* in = mode ? support : queries;

    const int t = threadIdx.x;
    const int w = t >> 6, l = t & 63, lg = l >> 4, ll = l & 15;
    const int wr = w & 1, wc = w >> 1;

    // pad rows to 36 shorts (72B=18 dwords): rows 0..15 hit distinct bank sets
    __shared__ unsigned short Alds[2][128][36];
    __shared__ unsigned short Blds[2][256][36];

    f32x4 acc[4][4];
    #pragma unroll
    for (int i = 0; i < 4; ++i)
        #pragma unroll
        for (int j = 0; j < 4; ++j) acc[i][j] = (f32x4){0.f, 0.f, 0.f, 0.f};

    const int srow = t >> 3, skc = (t & 7) * 4;          // 8 lanes per row
    const float* aptr = in + (size_t)(rowbase + srow) * 1024 + skc;
    const float* bptr = Wv + (size_t)(colbase + srow) * 1024 + skc;

    float4_t aReg[2], bReg[4];
    #pragma unroll
    for (int c = 0; c < 2; ++c) aReg[c] = *(const float4_t*)(aptr + (size_t)c * 64 * 1024);
    #pragma unroll
    for (int c = 0; c < 4; ++c) bReg[c] = *(const float4_t*)(bptr + (size_t)c * 64 * 1024);

    for (int kt = 0; kt < 32; ++kt) {
        const int cur = kt & 1;
        #pragma unroll
        for (int c = 0; c < 2; ++c)
            *(short4_t*)&Alds[cur][srow + c * 64][skc] = pack4(aReg[c]);
        #pragma unroll
        for (int c = 0; c < 4; ++c)
            *(short4_t*)&Blds[cur][srow + c * 64][skc] = pack4(bReg[c]);
        __syncthreads();
        if (kt < 31) {
            const int kb = (kt + 1) * 32;
            #pragma unroll
            for (int c = 0; c < 2; ++c) aReg[c] = *(const float4_t*)(aptr + (size_t)c * 64 * 1024 + kb);
            #pragma unroll
            for (int c = 0; c < 4; ++c) bReg[c] = *(const float4_t*)(bptr + (size_t)c * 64 * 1024 + kb);
        }
        bf16x8 af[4], bfr[4];
        #pragma unroll
        for (int mf = 0; mf < 4; ++mf) af[mf] = *(const bf16x8*)&Alds[cur][wr * 64 + mf * 16 + ll][lg * 8];
        #pragma unroll
        for (int nf = 0; nf < 4; ++nf) bfr[nf] = *(const bf16x8*)&Blds[cur][wc * 64 + nf * 16 + ll][lg * 8];
        #pragma unroll
        for (int mf = 0; mf < 4; ++mf)
            #pragma unroll
            for (int nf = 0; nf < 4; ++nf)
                acc[mf][nf] = MFMA16(af[mf], bfr[nf], acc[mf][nf]);
        __syncthreads();
    }

    float bvv[4];
    #pragma unroll
    for (int nf = 0; nf < 4; ++nf) bvv[nf] = bv[colbase + wc * 64 + nf * 16 + ll];

    if (mode == 0) {
        #pragma unroll
        for (int mf = 0; mf < 4; ++mf)
            #pragma unroll
            for (int r = 0; r < 4; ++r) {
                const size_t row = rowbase + wr * 64 + mf * 16 + lg * 4 + r;
                #pragma unroll
                for (int nf = 0; nf < 4; ++nf)
                    q_proto[row * 512 + colbase + wc * 64 + nf * 16 + ll] = acc[mf][nf][r] + bvv[nf];
            }
    } else {
        #pragma unroll
        for (int mf = 0; mf < 4; ++mf)
            #pragma unroll
            for (int nf = 0; nf < 4; ++nf) {
                float4_t pv = {acc[mf][nf][0] + bvv[nf], acc[mf][nf][1] + bvv[nf],
                               acc[mf][nf][2] + bvv[nf], acc[mf][nf][3] + bvv[nf]};
                const size_t col = colbase + wc * 64 + nf * 16 + ll;
                *(short4_t*)&VsT[col * 8192 + rowbase + wr * 64 + mf * 16 + lg * 4] = pack4(pv);
            }
    }
}

// ---------------------------------------------------------------------------
// proj_ln: dst = LN(in @ W^T + b) for modes {0: support/Wk->Ks, 1: queries/Wq->Qs}.
// BM=64, BN=512 (full row for LN), BK=32. grid 256 = 2 modes x 128 rowb.
// Wave grid 2r x 4c: wave owns 32 rows x 128 cols -> acc[2][8] (64 AGPR).
// ---------------------------------------------------------------------------
__global__ __launch_bounds__(512, 2) void proj_ln_kernel(
    const float* __restrict__ support, const float* __restrict__ queries,
    const float* __restrict__ Wk, const float* __restrict__ bk,
    const float* __restrict__ Wq, const float* __restrict__ bq,
    const float* __restrict__ gamma, const float* __restrict__ beta,
    unsigned short* __restrict__ Ks, unsigned short* __restrict__ Qs)
{
    const int mode = blockIdx.x >> 7;
    const int rowbase = (blockIdx.x & 127) * 64;
    const float* in = mode ? queries : support;
    const float* W = mode ? Wq : Wk;
    const float* bias = mode ? bq : bk;
    unsigned short* dst = mode ? Qs : Ks;

    const int t = threadIdx.x;
    const int w = t >> 6, l = t & 63, lg = l >> 4, ll = l & 15;
    const int wr = w & 1, wc = w >> 1;

    __shared__ unsigned short Alds[2][64][36];
    __shared__ unsigned short Blds[2][512][36];
    __shared__ float red[4][64][2];
    __shared__ float stats[64][2];

    f32x4 acc[2][8];
    #pragma unroll
    for (int i = 0; i < 2; ++i)
        #pragma unroll
        for (int j = 0; j < 8; ++j) acc[i][j] = (f32x4){0.f, 0.f, 0.f, 0.f};

    const int srow = t >> 3, skc = (t & 7) * 4;
    const float* aptr = in + (size_t)(rowbase + srow) * 1024 + skc;   // rows 0..63
    const float* bptr = W + (size_t)srow * 1024 + skc;                // rows +c*64

    float4_t aReg, bReg[8];
    aReg = *(const float4_t*)aptr;
    #pragma unroll
    for (int c = 0; c < 8; ++c) bReg[c] = *(const float4_t*)(bptr + (size_t)c * 64 * 1024);

    for (int kt = 0; kt < 32; ++kt) {
        const int cur = kt & 1;
        *(short4_t*)&Alds[cur][srow][skc] = pack4(aReg);
        #pragma unroll
        for (int c = 0; c < 8; ++c)
            *(short4_t*)&Blds[cur][srow + c * 64][skc] = pack4(bReg[c]);
        __syncthreads();
        if (kt < 31) {
            const int kb = (kt + 1) * 32;
            aReg = *(const float4_t*)(aptr + kb);
            #pragma unroll
            for (int c = 0; c < 8; ++c) bReg[c] = *(const float4_t*)(bptr + (size_t)c * 64 * 1024 + kb);
        }
        bf16x8 af[2], bfr[8];
        #pragma unroll
        for (int mf = 0; mf < 2; ++mf) af[mf] = *(const bf16x8*)&Alds[cur][wr * 32 + mf * 16 + ll][lg * 8];
        #pragma unroll
        for (int nf = 0; nf < 8; ++nf) bfr[nf] = *(const bf16x8*)&Blds[cur][wc * 128 + nf * 16 + ll][lg * 8];
        #pragma unroll
        for (int mf = 0; mf < 2; ++mf)
            #pragma unroll
            for (int nf = 0; nf < 8; ++nf)
                acc[mf][nf] = MFMA16(af[mf], bfr[nf], acc[mf][nf]);
        __syncthreads();
    }

    float bvv[8];
    #pragma unroll
    for (int nf = 0; nf < 8; ++nf) bvv[nf] = bias[wc * 128 + nf * 16 + ll];

    float v[2][8][4];
    #pragma unroll
    for (int mf = 0; mf < 2; ++mf)
        #pragma unroll
        for (int nf = 0; nf < 8; ++nf)
            #pragma unroll
            for (int r = 0; r < 4; ++r)
                v[mf][nf][r] = acc[mf][nf][r] + bvv[nf];

    #pragma unroll
    for (int mf = 0; mf < 2; ++mf)
        #pragma unroll
        for (int r = 0; r < 4; ++r) {
            float s = 0.f, q = 0.f;
            #pragma unroll
            for (int nf = 0; nf < 8; ++nf) { s += v[mf][nf][r]; q += v[mf][nf][r] * v[mf][nf][r]; }
            #pragma unroll
            for (int d = 1; d < 16; d <<= 1) { s += __shfl_xor(s, d); q += __shfl_xor(q, d); }
            if (ll == 0) {
                red[wc][wr * 32 + mf * 16 + lg * 4 + r][0] = s;
                red[wc][wr * 32 + mf * 16 + lg * 4 + r][1] = q;
            }
        }
    __syncthreads();
    if (t < 64) {
        float S = 0.f, Q = 0.f;
        #pragma unroll
        for (int w2 = 0; w2 < 4; ++w2) { S += red[w2][t][0]; Q += red[w2][t][1]; }
        const float mu = S * (1.f / 512.f);
        const float var = Q * (1.f / 512.f) - mu * mu;
        stats[t][0] = mu;
        stats[t][1] = rsqrtf(var + 1e-5f);
    }
    __syncthreads();
    float gv[8], bev[8];
    #pragma unroll
    for (int nf = 0; nf < 8; ++nf) {
        gv[nf] = gamma[wc * 128 + nf * 16 + ll];
        bev[nf] = beta[wc * 128 + nf * 16 + ll];
    }
    #pragma unroll
    for (int mf = 0; mf < 2; ++mf)
        #pragma unroll
        for (int r = 0; r < 4; ++r) {
            const int row = wr * 32 + mf * 16 + lg * 4 + r;
            const float mu = stats[row][0], rs = stats[row][1];
            #pragma unroll
            for (int nf = 0; nf < 8; ++nf) {
                const float o = (v[mf][nf][r] - mu) * rs * gv[nf] + bev[nf];
                dst[(size_t)(rowbase + row) * 512 + wc * 128 + nf * 16 + ll] = f2bf(o);
            }
        }
}

// ---------------------------------------------------------------------------
// Flash attention v4: BM=64 q-rows, BKV=64, kv-split 2, grid 256 (1 blk/CU).
// QK^T wave grid 4q x 2kv: wave reads only 32 K-rows (K redundancy halved).
// PV wave grid 1r x 8c: wave owns out-cols [w*64,w*64+64), all 64 rows.
// V prefetched into regs before the barrier (vmcnt drain covers it).
// P swizzle (row>>1)&7: write's 4 lg-rows map to 4 distinct swz -> all 8
// units distinct -> 2-way only (free). Reads stay 2-way.
// Single barrier per iter (K dbuf + P dbuf), hazards as in v3.
// LDS: 128KB K + 16KB P + 0.5KB lsum.
// ---------------------------------------------------------------------------
__global__ __launch_bounds__(512, 2) void attn_kernel(
    const unsigned short* __restrict__ Qs, const unsigned short* __restrict__ Ks,
    const unsigned short* __restrict__ VsT,
    float* __restrict__ Opart, float* __restrict__ lpart)
{
    const int bid = blockIdx.x;
    const int sp = (bid & 7) >> 2;              // kv half pinned per XCD group
    const int qb = (bid >> 3) * 4 + (bid & 3);  // 0..127
    const int qbase = qb * 64;
    const int kv0 = sp * 4096;
    const int t = threadIdx.x;
    const int w = t >> 6, l = t & 63, lg = l >> 4, ll = l & 15;
    const int wq = w & 3, wk = w >> 2;          // QK^T decomposition

    __shared__ unsigned short Klds[2][64][512];   // 128 KB, src-preswizzled
    __shared__ unsigned short Plds[2][64][64];    // 16 KB, (row>>1) swizzled
    __shared__ float lsum[2][64];

    // Q fragments: rows qbase + wq*16 + ll (64 VGPR), reused all 64 iters
    bf16x8 qf[16];
    {
        const unsigned short* qrow = Qs + (size_t)(qbase + wq * 16 + ll) * 512 + lg * 8;
        #pragma unroll
        for (int ks = 0; ks < 16; ++ks)
            qf[ks] = *(const bf16x8*)(qrow + ks * 32);
    }

    f32x4 oacc[4][4];
    #pragma unroll
    for (int i = 0; i < 4; ++i)
        #pragma unroll
        for (int j = 0; j < 4; ++j) oacc[i][j] = (f32x4){0.f, 0.f, 0.f, 0.f};
    float lrun[4] = {0.f, 0.f, 0.f, 0.f};
    const float scale = 0.044194173824159216f;  // 1/sqrt(512)

    // prologue: stage tile 0 (wave w rows w*8..+8, source col-unit ^ (r&7))
    #pragma unroll
    for (int rr = 0; rr < 8; ++rr) {
        const int r = w * 8 + rr;
        gload_lds16(Ks + (size_t)(kv0 + r) * 512 + ((l ^ (r & 7)) << 3),
                    &Klds[0][r][0]);
    }
    __syncthreads();

    for (int it = 0; it < 64; ++it) {
        const int cur = it & 1;
        const int kvb = kv0 + it * 64;

        if (it < 63) {
            const int kvn = kvb + 64;
            #pragma unroll
            for (int rr = 0; rr < 8; ++rr) {
                const int r = w * 8 + rr;
                gload_lds16(Ks + (size_t)(kvn + r) * 512 + ((l ^ (r & 7)) << 3),
                            &Klds[cur ^ 1][r][0]);
            }
        }

        // QK^T: wave (wq,wk): q-rows wq*16..+16, kv-cols wk*32..+32
        f32x4 sacc[2];
        sacc[0] = (f32x4){0.f, 0.f, 0.f, 0.f};
        sacc[1] = (f32x4){0.f, 0.f, 0.f, 0.f};
        __builtin_amdgcn_s_setprio(1);
        #pragma unroll
        for (int ks = 0; ks < 16; ++ks) {
            const int u = ((ks * 4 + lg) ^ (ll & 7)) * 8;   // row&7 == ll&7
            #pragma unroll
            for (int nf = 0; nf < 2; ++nf) {
                bf16x8 kf = *(const bf16x8*)&Klds[cur][wk * 32 + nf * 16 + ll][u];
                sacc[nf] = MFMA16(qf[ks], kf, sacc[nf]);
            }
        }
        __builtin_amdgcn_s_setprio(0);

        // V prefetch into regs (consumed in PV; drained by the barrier)
        bf16x8 vf[2][4];
        #pragma unroll
        for (int ks2 = 0; ks2 < 2; ++ks2)
            #pragma unroll
            for (int nf = 0; nf < 4; ++nf)
                vf[ks2][nf] = *(const bf16x8*)(VsT + (size_t)(w * 64 + nf * 16 + ll) * 8192
                                               + kvb + ks2 * 32 + lg * 8);

        // exp + P write into P[cur]
        #pragma unroll
        for (int r = 0; r < 4; ++r) {
            const int row = wq * 16 + lg * 4 + r;
            const int swz = (row >> 1) & 7;
            float rsum = 0.f;
            #pragma unroll
            for (int nf = 0; nf < 2; ++nf) {
                const float p = __expf(sacc[nf][r] * scale);
                rsum += p;
                const int col = wk * 32 + nf * 16 + ll;
                const int unit = (col >> 3) ^ swz;
                Plds[cur][row][unit * 8 + (col & 7)] = f2bf(p);
            }
            #pragma unroll
            for (int d = 1; d < 16; d <<= 1) rsum += __shfl_xor(rsum, d);
            lrun[r] += rsum;   // partial over this wave's 32 kv cols
        }

        __syncthreads();   // P[cur] ready, K[cur^1] staged, vf loaded

        // PV: wave w owns out-cols w*64..+64, all 64 q-rows
        __builtin_amdgcn_s_setprio(1);
        #pragma unroll
        for (int ks2 = 0; ks2 < 2; ++ks2) {
            #pragma unroll
            for (int mf = 0; mf < 4; ++mf) {
                const int row = mf * 16 + ll;
                const int unit = (ks2 * 4 + lg) ^ ((row >> 1) & 7);
                bf16x8 pf = *(const bf16x8*)&Plds[cur][row][unit * 8];
                #pragma unroll
                for (int nf = 0; nf < 4; ++nf)
                    oacc[mf][nf] = MFMA16(pf, vf[ks2][nf], oacc[mf][nf]);
            }
        }
        __builtin_amdgcn_s_setprio(0);
    }

    const size_t obase = (size_t)sp * 8192 + qbase;
    #pragma unroll
    for (int mf = 0; mf < 4; ++mf)
        #pragma unroll
        for (int r = 0; r < 4; ++r) {
            const size_t row = obase + mf * 16 + lg * 4 + r;
            #pragma unroll
            for (int nf = 0; nf < 4; ++nf)
                Opart[row * 512 + w * 64 + nf * 16 + ll] = oacc[mf][nf][r];
        }
    if (ll == 0) {
        #pragma unroll
        for (int r = 0; r < 4; ++r)
            lsum[wk][wq * 16 + lg * 4 + r] = lrun[r];
    }
    __syncthreads();
    if (t < 64)
        lpart[(size_t)sp * 8192 + qbase + t] = lsum[0][t] + lsum[1][t];
}

// ---------------------------------------------------------------------------
// Merge: out2 = (sum_s Opart[s]) / (sum_s lpart[s]), s in {0,1}
// ---------------------------------------------------------------------------
__global__ __launch_bounds__(256) void merge_kernel(
    const float* __restrict__ Opart, const float* __restrict__ lpart,
    float* __restrict__ out2)
{
    const int idx = blockIdx.x * 256 + threadIdx.x;
    const int q = idx >> 7;
    const int c = (idx & 127) * 4;
    float4_t a = {0.f, 0.f, 0.f, 0.f};
    float ls = 0.f;
    #pragma unroll
    for (int s = 0; s < 2; ++s) {
        float4_t vv = *(const float4_t*)(Opart + ((size_t)s * 8192 + q) * 512 + c);
        a += vv;
        ls += lpart[s * 8192 + q];
    }
    const float inv = 1.f / ls;
    *(float4_t*)(out2 + (size_t)q * 512 + c) = a * inv;
}

extern "C" void kernel_launch(void* const* d_in, const int* in_sizes, int n_in,
                              void* d_out, int out_size, void* d_ws, size_t ws_size,
                              hipStream_t stream)
{
    const float* support = (const float*)d_in[0];
    const float* queries = (const float*)d_in[1];
    const float* Wq = (const float*)d_in[2];
    const float* bq = (const float*)d_in[3];
    const float* Wk = (const float*)d_in[4];
    const float* bk = (const float*)d_in[5];
    const float* Wv = (const float*)d_in[6];
    const float* bv = (const float*)d_in[7];
    const float* gamma = (const float*)d_in[8];
    const float* beta = (const float*)d_in[9];

    float* out = (float*)d_out;
    float* q_proto = out;                       // output 0: [8192,512]
    float* out2 = out + (size_t)8192 * 512;     // output 1: [8192,512]

    char* ws = (char*)d_ws;
    unsigned short* Qs  = (unsigned short*)(ws);                      //  8 MB
    unsigned short* Ks  = (unsigned short*)(ws + ((size_t)8 << 20));  //  8 MB
    unsigned short* VsT = (unsigned short*)(ws + ((size_t)16 << 20)); //  8 MB
    float* Opart = (float*)(ws + ((size_t)24 << 20));                 // 32 MB
    float* lpart = (float*)(ws + ((size_t)56 << 20));                 // 64 KB

    proj_v_kernel<<<256, 512, 0, stream>>>(support, queries, Wv, bv, q_proto, VsT);
    proj_ln_kernel<<<256, 512, 0, stream>>>(support, queries, Wk, bk, Wq, bq,
                                            gamma, beta, Ks, Qs);
    attn_kernel<<<256, 512, 0, stream>>>(Qs, Ks, VsT, Opart, lpart);
    merge_kernel<<<4096, 256, 0, stream>>>(Opart, lpart, out2);
}